// Round 3
// baseline (69.714 us; speedup 1.0000x reference)
//
#include <hip/hip_runtime.h>
#include <hip/hip_fp16.h>

#define N_NODES 100000
#define N_EDGES 600000
#define DIM 128
#define HID 64
#define TILES_TOTAL (N_NODES / 16)   // 6250, exact

typedef __attribute__((ext_vector_type(8))) _Float16 half8;
typedef __attribute__((ext_vector_type(4))) _Float16 half4v;
typedef __attribute__((ext_vector_type(4))) float floatx4;

// ---------------------------------------------------------------------------
// Kernel 0: W1T[c][k] (f16, [128][128]) = c<64 ? W1[k][c] : W1[128+k][c-64]
// 32 KB — stays L1/L2 resident for the main kernel's fragment loads.
// ---------------------------------------------------------------------------
__global__ __launch_bounds__(256) void prep_W(
    const float* __restrict__ W1, __half* __restrict__ W1T)
{
    const int o = (int)(blockIdx.x * blockDim.x + threadIdx.x) * 2;
    if (o >= 128 * 128) return;
    const int c = o >> 7, k = o & 127;          // o even -> k, k+1 same c
    float w0, w1;
    if (c < HID) { w0 = W1[k * HID + c];           w1 = W1[(k + 1) * HID + c]; }
    else         { w0 = W1[(DIM + k) * HID + c - HID]; w1 = W1[(DIM + k + 1) * HID + c - HID]; }
    W1T[o]     = __float2half(w0);
    W1T[o + 1] = __float2half(w1);
}

// ---------------------------------------------------------------------------
// Kernel 1: P[n][c] = node_emb[n] @ Wbig[:,c] (+ b1[c] for c<64), P in f16.
// One 16-node tile per wave; no LDS. MFMA operands swapped (W as A-operand)
// so each lane's 4 acc regs are 4 CONSECUTIVE cols of one node row -> one
// 8-byte packed store each. W fragments load from L1-resident W1T.
// ---------------------------------------------------------------------------
__global__ __launch_bounds__(256) void precompute_P(
    const float* __restrict__ node_emb,
    const __half* __restrict__ W1T,
    const float* __restrict__ b1,
    __half* __restrict__ P)
{
    const int tid  = (int)(blockIdx.x * blockDim.x + threadIdx.x);
    const int t    = tid >> 6;
    if (t >= TILES_TOTAL) return;
    const int lane = tid & 63;
    const int lr   = lane & 15;          // node within tile / MFMA index
    const int q    = lane >> 4;
    const int kq   = q * 8;

    // A-side (node) data: row t*16+lr, k = 32*ks + kq + 0..7
    const float* arow = node_emb + (size_t)(t * 16 + lr) * DIM + kq;
    float4 a[4][2];
#pragma unroll
    for (int ks = 0; ks < 4; ks++) {
        a[ks][0] = *(const float4*)(arow + ks * 32);
        a[ks][1] = *(const float4*)(arow + ks * 32 + 4);
    }

    floatx4 acc[8];
#pragma unroll
    for (int nt = 0; nt < 8; nt++) acc[nt] = (floatx4){0.f, 0.f, 0.f, 0.f};

#pragma unroll
    for (int ks = 0; ks < 4; ks++) {
        half8 af;
        af[0] = (_Float16)a[ks][0].x; af[1] = (_Float16)a[ks][0].y;
        af[2] = (_Float16)a[ks][0].z; af[3] = (_Float16)a[ks][0].w;
        af[4] = (_Float16)a[ks][1].x; af[5] = (_Float16)a[ks][1].y;
        af[6] = (_Float16)a[ks][1].z; af[7] = (_Float16)a[ks][1].w;
#pragma unroll
        for (int nt = 0; nt < 8; nt++) {
            const half8 wf = *(const half8*)(W1T + (size_t)(nt * 16 + lr) * 128 + ks * 32 + kq);
            // swapped operands: D[row=c-in-tile][col=node-in-tile]
            acc[nt] = __builtin_amdgcn_mfma_f32_16x16x32_f16(wf, af, acc[nt], 0, 0, 0);
        }
    }

    // lane holds cols c0..c0+3 (c0 = nt*16 + 4q) of node row (t*16 + lr)
    __half* prow = P + (size_t)(t * 16 + lr) * 128;
#pragma unroll
    for (int nt = 0; nt < 8; nt++) {
        const int c0 = nt * 16 + q * 4;
        float v0 = acc[nt][0], v1 = acc[nt][1], v2 = acc[nt][2], v3 = acc[nt][3];
        if (nt < 4) {
            const float4 bs = *(const float4*)(b1 + c0);
            v0 += bs.x; v1 += bs.y; v2 += bs.z; v3 += bs.w;
        }
        half4v h;
        h[0] = (_Float16)v0; h[1] = (_Float16)v1;
        h[2] = (_Float16)v2; h[3] = (_Float16)v3;
        *(half4v*)(prow + c0) = h;
    }
}

// ---------------------------------------------------------------------------
__device__ inline bool detect_int64(const int* e32) {
    int orv = 0;
#pragma unroll
    for (int k = 0; k < 8; k++) orv |= e32[2 * k + 1];
    return orv == 0;
}

// ---------------------------------------------------------------------------
// Kernel 2: quarter-wave (16 lanes) per edge; lane j holds hidden units
// 4j..4j+3 as packed f16. 16 edges per wave iteration; 4-deep xor reduce.
// ---------------------------------------------------------------------------
__global__ __launch_bounds__(256) void edge_mlp(
    const __half* __restrict__ P,
    const void* __restrict__ eidx_raw,
    const float* __restrict__ W2,
    const float* __restrict__ b2,
    float* __restrict__ out)
{
    const int* e32 = (const int*)eidx_raw;
    const long long* e64 = (const long long*)eidx_raw;
    const bool is64 = detect_int64(e32);

    const int tid  = threadIdx.x;
    const int lane = tid & 63;
    const int j    = lane & 15;
    const int grp  = lane >> 4;
    const float4 w2 = *(const float4*)(W2 + 4 * j);
    const float b2v = b2[0];

    const int gwid   = (int)((blockIdx.x * blockDim.x + tid) >> 6);
    const int nwaves = (int)((gridDim.x * blockDim.x) >> 6);

    const half4v zero = {(_Float16)0, (_Float16)0, (_Float16)0, (_Float16)0};

    for (int base = gwid * 16; base < N_EDGES; base += nwaves * 16) {
        int s[4], d[4];
#pragma unroll
        for (int u = 0; u < 4; u++) {
            const int e = base + 4 * u + grp;
            if (is64) { s[u] = (int)e64[e]; d[u] = (int)e64[N_EDGES + e]; }
            else      { s[u] = e32[e];      d[u] = e32[N_EDGES + e]; }
        }
        half4v av[4], bv[4];
#pragma unroll
        for (int u = 0; u < 4; u++) {
            av[u] = *(const half4v*)(P + (size_t)s[u] * 128 + 4 * j);
            bv[u] = *(const half4v*)(P + (size_t)d[u] * 128 + 64 + 4 * j);
        }
#pragma unroll
        for (int u = 0; u < 4; u++) {
            const half4v t = av[u] + bv[u];                    // v_pk_add_f16
            const half4v r = __builtin_elementwise_max(t, zero);
            float acc = (float)r[0] * w2.x + (float)r[1] * w2.y
                      + (float)r[2] * w2.z + (float)r[3] * w2.w;
#pragma unroll
            for (int off = 8; off >= 1; off >>= 1)
                acc += __shfl_xor(acc, off, 64);
            if (j == 0) out[base + 4 * u + grp] = acc + b2v;
        }
    }
}

// ---------------------------------------------------------------------------
// Fallback (ws too small): direct per-edge compute, slow but correct.
// ---------------------------------------------------------------------------
__global__ __launch_bounds__(256) void edge_mlp_direct(
    const float* __restrict__ node_emb,
    const void* __restrict__ eidx_raw,
    const float* __restrict__ W1,
    const float* __restrict__ b1,
    const float* __restrict__ W2,
    const float* __restrict__ b2,
    float* __restrict__ out)
{
    const int* e32 = (const int*)eidx_raw;
    const long long* e64 = (const long long*)eidx_raw;
    const bool is64 = detect_int64(e32);

    const int lane = threadIdx.x & 63;
    const float w2  = W2[lane];
    const float b2v = b2[0];
    const int gwid   = (int)((blockIdx.x * blockDim.x + threadIdx.x) >> 6);
    const int nwaves = (int)((gridDim.x * blockDim.x) >> 6);

    for (int e = gwid; e < N_EDGES; e += nwaves) {
        int s, d;
        if (is64) { s = (int)e64[e]; d = (int)e64[N_EDGES + e]; }
        else      { s = e32[e];      d = e32[N_EDGES + e]; }
        const float* es = node_emb + (size_t)s * DIM;
        const float* ed = node_emb + (size_t)d * DIM;
        float acc = b1[lane];
        for (int k = 0; k < DIM; k++) {
            acc += es[k] * W1[k * HID + lane];
            acc += ed[k] * W1[(DIM + k) * HID + lane];
        }
        float t = fmaxf(acc, 0.f) * w2;
#pragma unroll
        for (int off = 32; off >= 1; off >>= 1)
            t += __shfl_xor(t, off, 64);
        if (lane == 0) out[e] = t + b2v;
    }
}

// ---------------------------------------------------------------------------
extern "C" void kernel_launch(void* const* d_in, const int* in_sizes, int n_in,
                              void* d_out, int out_size, void* d_ws, size_t ws_size,
                              hipStream_t stream) {
    const float* node_emb = (const float*)d_in[0];
    const void*  eidx     = d_in[1];
    const float* W1       = (const float*)d_in[2];
    const float* b1       = (const float*)d_in[3];
    const float* W2       = (const float*)d_in[4];
    const float* b2       = (const float*)d_in[5];
    float* out = (float*)d_out;

    const size_t pbytes   = (size_t)N_NODES * 128 * sizeof(__half);   // 25.6 MB
    const size_t wt_off   = 32u * 1024 * 1024;
    const size_t need     = wt_off + 128 * 128 * sizeof(__half);

    if (ws_size >= need) {
        __half* P   = (__half*)d_ws;
        __half* W1T = (__half*)((char*)d_ws + wt_off);
        prep_W<<<32, 256, 0, stream>>>(W1, W1T);
        precompute_P<<<(TILES_TOTAL * 64 + 255) / 256, 256, 0, stream>>>(node_emb, W1T, b1, P);
        edge_mlp<<<2048, 256, 0, stream>>>(P, eidx, W2, b2, out);
    } else if (ws_size >= pbytes) {
        // Shouldn't happen given harness ws sizing, but stay correct:
        __half* P = (__half*)d_ws;
        // reuse direct path for W; simplest correct fallback
        edge_mlp_direct<<<4096, 256, 0, stream>>>(node_emb, eidx, W1, b1, W2, b2, out);
        (void)P;
    } else {
        edge_mlp_direct<<<4096, 256, 0, stream>>>(node_emb, eidx, W1, b1, W2, b2, out);
    }
}

// Round 4
// 54.022 us; speedup vs baseline: 1.2905x; 1.2905x over previous
//
#include <hip/hip_runtime.h>
#include <hip/hip_fp16.h>

#define N_NODES 100000
#define N_EDGES 600000
#define DIM 128
#define HID 64
#define NCHUNK 1563          // ceil(100000 / 64)

typedef __attribute__((ext_vector_type(8))) _Float16 half8;
typedef __attribute__((ext_vector_type(4))) _Float16 half4v;
typedef __attribute__((ext_vector_type(4))) float floatx4;

// direct global -> LDS, 16 B per lane (dest must be lane-linear!)
__device__ __forceinline__ void gload_lds16(const void* g, void* l) {
    __builtin_amdgcn_global_load_lds(
        (const __attribute__((address_space(1))) void*)g,
        (__attribute__((address_space(3))) void*)l, 16, 0, 0);
}

// ---------------------------------------------------------------------------
// Kernel 0: W1T[c][k] (f16, [128][128]) = c<64 ? W1[k][c] : W1[128+k][c-64]
// ---------------------------------------------------------------------------
__global__ __launch_bounds__(256) void prep_W(
    const float* __restrict__ W1, __half* __restrict__ W1T)
{
    const int o = (int)(blockIdx.x * blockDim.x + threadIdx.x) * 2;
    if (o >= 128 * 128) return;
    const int c = o >> 7, k = o & 127;
    float w0, w1;
    if (c < HID) { w0 = W1[k * HID + c];               w1 = W1[(k + 1) * HID + c]; }
    else         { w0 = W1[(DIM + k) * HID + c - HID]; w1 = W1[(DIM + k + 1) * HID + c - HID]; }
    W1T[o]     = __float2half(w0);
    W1T[o + 1] = __float2half(w1);
}

// ---------------------------------------------------------------------------
// Kernel 1: P = node_emb @ Wbig (+b1 on cols 0..63), f16 out.
// 2-phase pipeline: 64-row chunk double-buffered in LDS via global_load_lds
// (source pre-swizzled with XOR (row&7)<<4 so ds_read_b128 is spread over
// banks); W fragments live in registers; counted vmcnt(8), never drain-0.
// ---------------------------------------------------------------------------
__global__ __launch_bounds__(256, 2) void precompute_P(
    const float* __restrict__ node_emb,
    const __half* __restrict__ W1T,
    const float* __restrict__ b1,
    __half* __restrict__ P)
{
    __shared__ float Abuf[2][64 * 128];          // 2 x 32 KB

    const int tid  = threadIdx.x;
    const int w    = tid >> 6;
    const int lane = tid & 63;
    const int lr   = lane & 15;
    const int q    = lane >> 4;

    // W fragments -> 128 VGPRs (once per block; W1T is L2-hot, 32 KB)
    half8 wf[8][4];
#pragma unroll
    for (int nt = 0; nt < 8; nt++)
#pragma unroll
        for (int ks = 0; ks < 4; ks++)
            wf[nt][ks] = *(const half8*)(W1T + (size_t)(nt * 16 + lr) * 128 + ks * 32 + q * 8);

    float4 bias4[4];
#pragma unroll
    for (int nt = 0; nt < 4; nt++)
        bias4[nt] = *(const float4*)(b1 + nt * 16 + q * 4);

    // staging geometry: round r stages rows r*8 .. r*8+7 of the chunk;
    // thread covers (row_in = r*8 + tid/32, inner byte = (tid&31)*16).
    const int r8   = tid >> 5;
    const int in16 = (tid & 31) << 4;
    const char* nb = (const char*)node_emb;

    int c = (int)blockIdx.x;
    // prologue: stage chunk c into buf 0
#pragma unroll
    for (int r = 0; r < 8; r++) {
        int row_in = r * 8 + r8;
        int grow = c * 64 + row_in;
        if (grow >= N_NODES) grow = N_NODES - 1;
        const size_t src = (size_t)grow * 512 + (size_t)(in16 ^ ((row_in & 7) << 4));
        gload_lds16(nb + src, (char*)&Abuf[0][0] + (r * 4096 + tid * 16));
    }

    int cur = 0;
    for (; c < NCHUNK; c += (int)gridDim.x, cur ^= 1) {
        const int cnext = c + (int)gridDim.x;
        if (cnext < NCHUNK) {
            // issue next chunk's stage into the other buffer BEFORE waiting
#pragma unroll
            for (int r = 0; r < 8; r++) {
                int row_in = r * 8 + r8;
                int grow = cnext * 64 + row_in;
                if (grow >= N_NODES) grow = N_NODES - 1;
                const size_t src = (size_t)grow * 512 + (size_t)(in16 ^ ((row_in & 7) << 4));
                gload_lds16(nb + src, (char*)&Abuf[cur ^ 1][0] + (r * 4096 + tid * 16));
            }
            asm volatile("s_waitcnt vmcnt(8)" ::: "memory");   // cur buf landed
        } else {
            asm volatile("s_waitcnt vmcnt(0)" ::: "memory");
        }
        __builtin_amdgcn_s_barrier();

        // wave w computes chunk rows w*16 .. w*16+15
        floatx4 acc[8];
#pragma unroll
        for (int nt = 0; nt < 8; nt++) acc[nt] = (floatx4){0.f, 0.f, 0.f, 0.f};

        const char* Ab = (const char*)&Abuf[cur][0];
        const int rb = w * 16 + lr;
        const int sw = (rb & 7) << 4;
#pragma unroll
        for (int ks = 0; ks < 4; ks++) {
            const int cb = ks * 128 + q * 32;
            const float4 x0 = *(const float4*)(Ab + rb * 512 + ((cb)      ^ sw));
            const float4 x1 = *(const float4*)(Ab + rb * 512 + ((cb + 16) ^ sw));
            half8 af;
            af[0] = (_Float16)x0.x; af[1] = (_Float16)x0.y;
            af[2] = (_Float16)x0.z; af[3] = (_Float16)x0.w;
            af[4] = (_Float16)x1.x; af[5] = (_Float16)x1.y;
            af[6] = (_Float16)x1.z; af[7] = (_Float16)x1.w;
#pragma unroll
            for (int nt = 0; nt < 8; nt++)
                acc[nt] = __builtin_amdgcn_mfma_f32_16x16x32_f16(wf[nt][ks], af, acc[nt], 0, 0, 0);
        }

        const int grow = c * 64 + w * 16 + lr;
        if (grow < N_NODES) {
            __half* prow = P + (size_t)grow * 128;
#pragma unroll
            for (int nt = 0; nt < 8; nt++) {
                const int c0 = nt * 16 + q * 4;
                float v0 = acc[nt][0], v1 = acc[nt][1], v2 = acc[nt][2], v3 = acc[nt][3];
                if (nt < 4) { v0 += bias4[nt].x; v1 += bias4[nt].y;
                              v2 += bias4[nt].z; v3 += bias4[nt].w; }
                half4v h;
                h[0] = (_Float16)v0; h[1] = (_Float16)v1;
                h[2] = (_Float16)v2; h[3] = (_Float16)v3;
                *(half4v*)(prow + c0) = h;
            }
        }
        __builtin_amdgcn_s_barrier();   // all waves done reading buf[cur]
    }
}

// ---------------------------------------------------------------------------
__device__ inline bool detect_int64(const int* e32) {
    int orv = 0;
#pragma unroll
    for (int k = 0; k < 8; k++) orv |= e32[2 * k + 1];
    return orv == 0;
}

// ---------------------------------------------------------------------------
// Kernel 2: quarter-wave (16 lanes) per edge; lane j holds hidden units
// 4j..4j+3 as packed f16. 16 edges per wave iteration; 4-deep xor reduce.
// ---------------------------------------------------------------------------
__global__ __launch_bounds__(256) void edge_mlp(
    const __half* __restrict__ P,
    const void* __restrict__ eidx_raw,
    const float* __restrict__ W2,
    const float* __restrict__ b2,
    float* __restrict__ out)
{
    const int* e32 = (const int*)eidx_raw;
    const long long* e64 = (const long long*)eidx_raw;
    const bool is64 = detect_int64(e32);

    const int tid  = threadIdx.x;
    const int lane = tid & 63;
    const int j    = lane & 15;
    const int grp  = lane >> 4;
    const float4 w2 = *(const float4*)(W2 + 4 * j);
    const float b2v = b2[0];

    const int gwid   = (int)((blockIdx.x * blockDim.x + tid) >> 6);
    const int nwaves = (int)((gridDim.x * blockDim.x) >> 6);

    const half4v zero = {(_Float16)0, (_Float16)0, (_Float16)0, (_Float16)0};

    for (int base = gwid * 16; base < N_EDGES; base += nwaves * 16) {
        int s[4], d[4];
#pragma unroll
        for (int u = 0; u < 4; u++) {
            const int e = base + 4 * u + grp;
            if (is64) { s[u] = (int)e64[e]; d[u] = (int)e64[N_EDGES + e]; }
            else      { s[u] = e32[e];      d[u] = e32[N_EDGES + e]; }
        }
        half4v av[4], bv[4];
#pragma unroll
        for (int u = 0; u < 4; u++) {
            av[u] = *(const half4v*)(P + (size_t)s[u] * 128 + 4 * j);
            bv[u] = *(const half4v*)(P + (size_t)d[u] * 128 + 64 + 4 * j);
        }
#pragma unroll
        for (int u = 0; u < 4; u++) {
            const half4v t = av[u] + bv[u];                    // v_pk_add_f16
            const half4v r = __builtin_elementwise_max(t, zero);
            float acc = (float)r[0] * w2.x + (float)r[1] * w2.y
                      + (float)r[2] * w2.z + (float)r[3] * w2.w;
#pragma unroll
            for (int off = 8; off >= 1; off >>= 1)
                acc += __shfl_xor(acc, off, 64);
            if (j == 0) out[base + 4 * u + grp] = acc + b2v;
        }
    }
}

// ---------------------------------------------------------------------------
// Fallback (ws too small): direct per-edge compute, slow but correct.
// ---------------------------------------------------------------------------
__global__ __launch_bounds__(256) void edge_mlp_direct(
    const float* __restrict__ node_emb,
    const void* __restrict__ eidx_raw,
    const float* __restrict__ W1,
    const float* __restrict__ b1,
    const float* __restrict__ W2,
    const float* __restrict__ b2,
    float* __restrict__ out)
{
    const int* e32 = (const int*)eidx_raw;
    const long long* e64 = (const long long*)eidx_raw;
    const bool is64 = detect_int64(e32);

    const int lane = threadIdx.x & 63;
    const float w2  = W2[lane];
    const float b2v = b2[0];
    const int gwid   = (int)((blockIdx.x * blockDim.x + threadIdx.x) >> 6);
    const int nwaves = (int)((gridDim.x * blockDim.x) >> 6);

    for (int e = gwid; e < N_EDGES; e += nwaves) {
        int s, d;
        if (is64) { s = (int)e64[e]; d = (int)e64[N_EDGES + e]; }
        else      { s = e32[e];      d = e32[N_EDGES + e]; }
        const float* es = node_emb + (size_t)s * DIM;
        const float* ed = node_emb + (size_t)d * DIM;
        float acc = b1[lane];
        for (int k = 0; k < DIM; k++) {
            acc += es[k] * W1[k * HID + lane];
            acc += ed[k] * W1[(DIM + k) * HID + lane];
        }
        float t = fmaxf(acc, 0.f) * w2;
#pragma unroll
        for (int off = 32; off >= 1; off >>= 1)
            t += __shfl_xor(t, off, 64);
        if (lane == 0) out[e] = t + b2v;
    }
}

// ---------------------------------------------------------------------------
extern "C" void kernel_launch(void* const* d_in, const int* in_sizes, int n_in,
                              void* d_out, int out_size, void* d_ws, size_t ws_size,
                              hipStream_t stream) {
    const float* node_emb = (const float*)d_in[0];
    const void*  eidx     = d_in[1];
    const float* W1       = (const float*)d_in[2];
    const float* b1       = (const float*)d_in[3];
    const float* W2       = (const float*)d_in[4];
    const float* b2       = (const float*)d_in[5];
    float* out = (float*)d_out;

    const size_t wt_off = 32u * 1024 * 1024;
    const size_t need   = wt_off + 128 * 128 * sizeof(__half);

    if (ws_size >= need) {
        __half* P   = (__half*)d_ws;
        __half* W1T = (__half*)((char*)d_ws + wt_off);
        prep_W<<<32, 256, 0, stream>>>(W1, W1T);
        precompute_P<<<512, 256, 0, stream>>>(node_emb, W1T, b1, P);
        edge_mlp<<<2048, 256, 0, stream>>>(P, eidx, W2, b2, out);
    } else {
        edge_mlp_direct<<<4096, 256, 0, stream>>>(node_emb, eidx, W1, b1, W2, b2, out);
    }
}

// Round 5
// 51.182 us; speedup vs baseline: 1.3621x; 1.0555x over previous
//
#include <hip/hip_runtime.h>
#include <hip/hip_fp16.h>

#define N_NODES 100000
#define N_EDGES 600000
#define DIM 128
#define HID 64
#define NCHUNK 1563          // ceil(100000 / 64)

typedef __attribute__((ext_vector_type(8))) _Float16 half8;
typedef __attribute__((ext_vector_type(4))) _Float16 half4v;
typedef __attribute__((ext_vector_type(4))) float floatx4;

// direct global -> LDS, 16 B per lane (dest must be lane-linear!)
__device__ __forceinline__ void gload_lds16(const void* g, void* l) {
    __builtin_amdgcn_global_load_lds(
        (const __attribute__((address_space(1))) void*)g,
        (__attribute__((address_space(3))) void*)l, 16, 0, 0);
}

// ---------------------------------------------------------------------------
// Kernel 0: W1T[c][k] (f16, [128][128]) = c<64 ? W1[k][c] : W1[128+k][c-64]
// ---------------------------------------------------------------------------
__global__ __launch_bounds__(256) void prep_W(
    const float* __restrict__ W1, __half* __restrict__ W1T)
{
    const int o = (int)(blockIdx.x * blockDim.x + threadIdx.x) * 2;
    if (o >= 128 * 128) return;
    const int c = o >> 7, k = o & 127;
    float w0, w1;
    if (c < HID) { w0 = W1[k * HID + c];               w1 = W1[(k + 1) * HID + c]; }
    else         { w0 = W1[(DIM + k) * HID + c - HID]; w1 = W1[(DIM + k + 1) * HID + c - HID]; }
    W1T[o]     = __float2half(w0);
    W1T[o + 1] = __float2half(w1);
}

// ---------------------------------------------------------------------------
// Kernel 1: P = node_emb @ Wbig (+b1 on hidden-funcs 0..63), f16 out.
// 2-phase global_load_lds pipeline (as R4). NEW: permuted epilogue — hidden
// unit h=(2m+t)*16+4q+i is stored at P-pos p=32m+8q+4t+i, so each lane emits
// 4x16B stores (even/odd tile pair packed) instead of 8x8B. Edge kernel
// reads W2 through the matching permutation.
// ---------------------------------------------------------------------------
__global__ __launch_bounds__(256, 2) void precompute_P(
    const float* __restrict__ node_emb,
    const __half* __restrict__ W1T,
    const float* __restrict__ b1,
    __half* __restrict__ P)
{
    __shared__ float Abuf[2][64 * 128];          // 2 x 32 KB

    const int tid  = threadIdx.x;
    const int w    = tid >> 6;
    const int lane = tid & 63;
    const int lr   = lane & 15;
    const int q    = lane >> 4;

    // W fragments -> 128 VGPRs (once per block; W1T is L2-hot, 32 KB)
    half8 wf[8][4];
#pragma unroll
    for (int nt = 0; nt < 8; nt++)
#pragma unroll
        for (int ks = 0; ks < 4; ks++)
            wf[nt][ks] = *(const half8*)(W1T + (size_t)(nt * 16 + lr) * 128 + ks * 32 + q * 8);

    float bias_[4][4];
#pragma unroll
    for (int nt = 0; nt < 4; nt++) {
        const float4 b4 = *(const float4*)(b1 + nt * 16 + q * 4);
        bias_[nt][0] = b4.x; bias_[nt][1] = b4.y;
        bias_[nt][2] = b4.z; bias_[nt][3] = b4.w;
    }

    // staging geometry: round r stages rows r*8 .. r*8+7 of the chunk;
    // thread covers (row_in = r*8 + tid/32, inner byte = (tid&31)*16).
    const int r8   = tid >> 5;
    const int in16 = (tid & 31) << 4;
    const char* nb = (const char*)node_emb;

    int c = (int)blockIdx.x;
    // prologue: stage chunk c into buf 0
#pragma unroll
    for (int r = 0; r < 8; r++) {
        int row_in = r * 8 + r8;
        int grow = c * 64 + row_in;
        if (grow >= N_NODES) grow = N_NODES - 1;
        const size_t src = (size_t)grow * 512 + (size_t)(in16 ^ ((row_in & 7) << 4));
        gload_lds16(nb + src, (char*)&Abuf[0][0] + (r * 4096 + tid * 16));
    }

    int cur = 0;
    for (; c < NCHUNK; c += (int)gridDim.x, cur ^= 1) {
        const int cnext = c + (int)gridDim.x;
        if (cnext < NCHUNK) {
            // issue next chunk's stage into the other buffer BEFORE waiting
#pragma unroll
            for (int r = 0; r < 8; r++) {
                int row_in = r * 8 + r8;
                int grow = cnext * 64 + row_in;
                if (grow >= N_NODES) grow = N_NODES - 1;
                const size_t src = (size_t)grow * 512 + (size_t)(in16 ^ ((row_in & 7) << 4));
                gload_lds16(nb + src, (char*)&Abuf[cur ^ 1][0] + (r * 4096 + tid * 16));
            }
            asm volatile("s_waitcnt vmcnt(8)" ::: "memory");   // cur buf landed
        } else {
            asm volatile("s_waitcnt vmcnt(0)" ::: "memory");
        }
        __builtin_amdgcn_s_barrier();

        // wave w computes chunk rows w*16 .. w*16+15
        floatx4 acc[8];
#pragma unroll
        for (int nt = 0; nt < 8; nt++) acc[nt] = (floatx4){0.f, 0.f, 0.f, 0.f};

        const char* Ab = (const char*)&Abuf[cur][0];
        const int rb = w * 16 + lr;
        const int sw = (rb & 7) << 4;
#pragma unroll
        for (int ks = 0; ks < 4; ks++) {
            const int cb = ks * 128 + q * 32;
            const float4 x0 = *(const float4*)(Ab + rb * 512 + ((cb)      ^ sw));
            const float4 x1 = *(const float4*)(Ab + rb * 512 + ((cb + 16) ^ sw));
            half8 af;
            af[0] = (_Float16)x0.x; af[1] = (_Float16)x0.y;
            af[2] = (_Float16)x0.z; af[3] = (_Float16)x0.w;
            af[4] = (_Float16)x1.x; af[5] = (_Float16)x1.y;
            af[6] = (_Float16)x1.z; af[7] = (_Float16)x1.w;
#pragma unroll
            for (int nt = 0; nt < 8; nt++)
                acc[nt] = __builtin_amdgcn_mfma_f32_16x16x32_f16(wf[nt][ks], af, acc[nt], 0, 0, 0);
        }

        const int grow = c * 64 + w * 16 + lr;
        if (grow < N_NODES) {
            char* prow = (char*)P + (size_t)grow * 256;
#pragma unroll
            for (int m = 0; m < 4; m++) {
                half8 hh;
#pragma unroll
                for (int i = 0; i < 4; i++) {
                    float va = acc[2 * m][i];
                    float vb = acc[2 * m + 1][i];
                    if (m < 2) {                       // tiles 2m, 2m+1 < 4
                        va += bias_[2 * m][i];
                        vb += bias_[2 * m + 1][i];
                    }
                    hh[i]     = (_Float16)va;
                    hh[i + 4] = (_Float16)vb;
                }
                *(half8*)(prow + m * 64 + q * 16) = hh;
            }
        }
        __builtin_amdgcn_s_barrier();   // all waves done reading buf[cur]
    }
}

// ---------------------------------------------------------------------------
__device__ inline bool detect_int64(const int* e32) {
    int orv = 0;
#pragma unroll
    for (int k = 0; k < 8; k++) orv |= e32[2 * k + 1];
    return orv == 0;
}

// ---------------------------------------------------------------------------
// Kernel 2: quarter-wave (16 lanes) per edge; lane j holds P-positions
// 4j..4j+3 (permuted hidden units). W2 is read through the inverse
// permutation: hbase = 32*(j>>3) + 16*(j&1) + 4*((j>>1)&3).
// ---------------------------------------------------------------------------
__global__ __launch_bounds__(256) void edge_mlp(
    const __half* __restrict__ P,
    const void* __restrict__ eidx_raw,
    const float* __restrict__ W2,
    const float* __restrict__ b2,
    float* __restrict__ out)
{
    const int* e32 = (const int*)eidx_raw;
    const long long* e64 = (const long long*)eidx_raw;
    const bool is64 = detect_int64(e32);

    const int tid  = threadIdx.x;
    const int lane = tid & 63;
    const int j    = lane & 15;
    const int grp  = lane >> 4;
    const int hbase = ((j >> 3) << 5) + ((j & 1) << 4) + (((j >> 1) & 3) << 2);
    const float4 w2 = *(const float4*)(W2 + hbase);
    const float b2v = b2[0];

    const int gwid   = (int)((blockIdx.x * blockDim.x + tid) >> 6);
    const int nwaves = (int)((gridDim.x * blockDim.x) >> 6);

    const half4v zero = {(_Float16)0, (_Float16)0, (_Float16)0, (_Float16)0};

    for (int base = gwid * 16; base < N_EDGES; base += nwaves * 16) {
        int s[4], d[4];
#pragma unroll
        for (int u = 0; u < 4; u++) {
            const int e = base + 4 * u + grp;
            if (is64) { s[u] = (int)e64[e]; d[u] = (int)e64[N_EDGES + e]; }
            else      { s[u] = e32[e];      d[u] = e32[N_EDGES + e]; }
        }
        half4v av[4], bv[4];
#pragma unroll
        for (int u = 0; u < 4; u++) {
            av[u] = *(const half4v*)(P + (size_t)s[u] * 128 + 4 * j);
            bv[u] = *(const half4v*)(P + (size_t)d[u] * 128 + 64 + 4 * j);
        }
#pragma unroll
        for (int u = 0; u < 4; u++) {
            const half4v t = av[u] + bv[u];                    // v_pk_add_f16
            const half4v r = __builtin_elementwise_max(t, zero);
            float acc = (float)r[0] * w2.x + (float)r[1] * w2.y
                      + (float)r[2] * w2.z + (float)r[3] * w2.w;
#pragma unroll
            for (int off = 8; off >= 1; off >>= 1)
                acc += __shfl_xor(acc, off, 64);
            if (j == 0) out[base + 4 * u + grp] = acc + b2v;
        }
    }
}

// ---------------------------------------------------------------------------
// Fallback (ws too small): direct per-edge compute, slow but correct.
// ---------------------------------------------------------------------------
__global__ __launch_bounds__(256) void edge_mlp_direct(
    const float* __restrict__ node_emb,
    const void* __restrict__ eidx_raw,
    const float* __restrict__ W1,
    const float* __restrict__ b1,
    const float* __restrict__ W2,
    const float* __restrict__ b2,
    float* __restrict__ out)
{
    const int* e32 = (const int*)eidx_raw;
    const long long* e64 = (const long long*)eidx_raw;
    const bool is64 = detect_int64(e32);

    const int lane = threadIdx.x & 63;
    const float w2  = W2[lane];
    const float b2v = b2[0];
    const int gwid   = (int)((blockIdx.x * blockDim.x + threadIdx.x) >> 6);
    const int nwaves = (int)((gridDim.x * blockDim.x) >> 6);

    for (int e = gwid; e < N_EDGES; e += nwaves) {
        int s, d;
        if (is64) { s = (int)e64[e]; d = (int)e64[N_EDGES + e]; }
        else      { s = e32[e];      d = e32[N_EDGES + e]; }
        const float* es = node_emb + (size_t)s * DIM;
        const float* ed = node_emb + (size_t)d * DIM;
        float acc = b1[lane];
        for (int k = 0; k < DIM; k++) {
            acc += es[k] * W1[k * HID + lane];
            acc += ed[k] * W1[(DIM + k) * HID + lane];
        }
        float t = fmaxf(acc, 0.f) * w2;
#pragma unroll
        for (int off = 32; off >= 1; off >>= 1)
            t += __shfl_xor(t, off, 64);
        if (lane == 0) out[e] = t + b2v;
    }
}

// ---------------------------------------------------------------------------
extern "C" void kernel_launch(void* const* d_in, const int* in_sizes, int n_in,
                              void* d_out, int out_size, void* d_ws, size_t ws_size,
                              hipStream_t stream) {
    const float* node_emb = (const float*)d_in[0];
    const void*  eidx     = d_in[1];
    const float* W1       = (const float*)d_in[2];
    const float* b1       = (const float*)d_in[3];
    const float* W2       = (const float*)d_in[4];
    const float* b2       = (const float*)d_in[5];
    float* out = (float*)d_out;

    const size_t wt_off = 32u * 1024 * 1024;
    const size_t need   = wt_off + 128 * 128 * sizeof(__half);

    if (ws_size >= need) {
        __half* P   = (__half*)d_ws;
        __half* W1T = (__half*)((char*)d_ws + wt_off);
        prep_W<<<32, 256, 0, stream>>>(W1, W1T);
        precompute_P<<<512, 256, 0, stream>>>(node_emb, W1T, b1, P);
        edge_mlp<<<2048, 256, 0, stream>>>(P, eidx, W2, b2, out);
    } else {
        edge_mlp_direct<<<4096, 256, 0, stream>>>(node_emb, eidx, W1, b1, W2, b2, out);
    }
}